// Round 8
// baseline (137.161 us; speedup 1.0000x reference)
//
#include <hip/hip_runtime.h>
#include <cstdint>

#define N_PTS 65536
#define DIM   1024
#define K_CL  256
#define BN    128
#define BK    32
#define NT    (DIM / BK)   // 32 k-tiles
#define THREADS 512

typedef __bf16 bf16_t;
typedef bf16_t bf16x8 __attribute__((ext_vector_type(8)));
typedef float  f32x4  __attribute__((ext_vector_type(4)));

union U16x8 { uint4 u4; bf16x8 bf; ushort us[8]; };

__device__ __forceinline__ ushort f2bf_rne(float f) {
    uint32_t u = __float_as_uint(f);
    uint32_t r = (u + 0x7FFFu + ((u >> 16) & 1u)) >> 16;
    return (ushort)r;
}
__device__ __forceinline__ float bf2f(ushort b) {
    return __uint_as_float(((uint32_t)b) << 16);
}

__device__ __forceinline__ void gll16(const void* g, void* l) {
    __builtin_amdgcn_global_load_lds(
        (const __attribute__((address_space(1))) void*)g,
        (__attribute__((address_space(3))) void*)l, 16, 0, 0);
}

#define BAR()   __builtin_amdgcn_s_barrier()
#define SCHB()  __builtin_amdgcn_sched_barrier(0)
#define LGKM0() do { asm volatile("s_waitcnt lgkmcnt(0)" ::: "memory"); \
                     __builtin_amdgcn_sched_barrier(0); } while (0)
#define VMCNT(N) do { asm volatile("s_waitcnt vmcnt(" #N ")" ::: "memory"); \
                      __builtin_amdgcn_sched_barrier(0); } while (0)
#define MFMA(ACC, A, B) (ACC) = __builtin_amdgcn_mfma_f32_16x16x32_bf16((A).bf, (B).bf, (ACC), 0, 0, 0)

// ---------------------------------------------------------------------------
// Kernel 0: centroids fp32 -> pre-swizzled bf16 hi/lo tile images + c_sq.
// (unchanged from r1-r7; layout verified)
// ---------------------------------------------------------------------------
__global__ __launch_bounds__(128) void km_prep(const float* __restrict__ cent,
                                               ushort* __restrict__ Ahi,
                                               ushort* __restrict__ Alo,
                                               float* __restrict__ csq) {
    const int r  = blockIdx.x;        // centroid row 0..255
    const int j  = threadIdx.x;       // 0..127
    const int kt = j >> 2;
    const int gp = j & 3;
    const int s  = (r >> 1) & 3;
    const int d0 = kt * BK + ((gp ^ s) << 3);

    const float* src = cent + r * DIM + d0;
    float4 a = *(const float4*)src;
    float4 b = *(const float4*)(src + 4);
    float v[8] = {a.x, a.y, a.z, a.w, b.x, b.y, b.z, b.w};

    U16x8 hi, lo;
    float ss = 0.f;
#pragma unroll
    for (int i = 0; i < 8; ++i) {
        float f = v[i];
        ss += f * f;
        ushort h = f2bf_rne(f);
        hi.us[i] = h;
        lo.us[i] = f2bf_rne(f - bf2f(h));
    }
    *(uint4*)(Ahi + kt * (K_CL * BK) + r * BK + gp * 8) = hi.u4;
    *(uint4*)(Alo + kt * (K_CL * BK) + r * BK + gp * 8) = lo.u4;

#pragma unroll
    for (int off = 1; off < 64; off <<= 1) ss += __shfl_xor(ss, off);
    __shared__ float ws2[2];
    if ((j & 63) == 0) ws2[j >> 6] = ss;
    __syncthreads();
    if (j == 0) csq[r] = ws2[0] + ws2[1];
}

// ---------------------------------------------------------------------------
// Kernel 1: fused distances + argmin + loss partial.
// Block = 512 thr (8 waves), tile 256 (all K) x 128 cols; wave = 64 x 64.
// A: 3-slot LDS ring, glls for kt+2 issued at kt (2-K-step pipeline depth;
// the binding wait is the compiler's vmcnt at the kt+1 convert - never hot).
// B: 2-slot dbuf, converted from regs one K-step ahead.
// 3 phases/kt, each 16 MFMA with <=8 ds_reads:
//   ph0 {ah x4 + b01 reads | gll A(kt+2)hi | hh+hl fj01}
//   ph1 {b23 reads         | gll A(kt+2)lo | hh+hl fj23}
//   ph2 {al x4 reads | convert+write B(kt+1) | bload(kt+2) | lh fj0-3}
//   VMCNT(6) once per kt (6 = glls(kt+2) x4 + bload(kt+2) x2 in flight).
// Split-bf16: hh + hl + lh; per-acc product order identical to r7.
// ---------------------------------------------------------------------------
__global__ __launch_bounds__(THREADS, 2) void km_main(
    const float* __restrict__ x,
    const ushort* __restrict__ Ahi, const ushort* __restrict__ Alo,
    const float* __restrict__ csq,
    float* __restrict__ out_dist, float* __restrict__ out_assign,
    float* __restrict__ partials) {

    __shared__ __align__(16) ushort sAhi[3][K_CL * BK];   // 48 KB
    __shared__ __align__(16) ushort sAlo[3][K_CL * BK];   // 48 KB
    __shared__ __align__(16) ushort sBhi[2][BN * BK];     // 16 KB
    __shared__ __align__(16) ushort sBlo[2][BN * BK];     // 16 KB
    __shared__ __align__(16) float  sCsq[K_CL];
    __shared__ __align__(16) float  sXsq[BN];
    __shared__ float sRedV[4 * BN];
    __shared__ int   sRedI[4 * BN];
    __shared__ float sWsum[8];

    const int tid  = threadIdx.x;
    const int blk  = blockIdx.x;
    const int lane = tid & 63;
    const int w    = tid >> 6;
    const int wr   = w >> 1;      // 0..3 row group (64 rows)
    const int wc   = w & 1;       // 0..1 col group (64 cols)
    const int l15  = lane & 15;
    const int l4   = lane >> 4;   // 0..3

    if (tid < K_CL) sCsq[tid] = csq[tid];

    // B staging: 4 threads per column, 8 d-elements each.
    const int bcol = tid >> 2;                  // 0..127
    const int bq   = tid & 3;                   // d-group 0..3 (8 elems)
    const int bs   = (bcol >> 1) & 3;           // swizzle key
    const int bOffW = bcol * BK + ((bq ^ bs) << 3);
    const float* xsrc = x + (size_t)(blk * BN + bcol) * DIM + bq * 8;

    float xs_acc = 0.f;

    // A staging: 16 KB per split per tile / 512 thr = 2 gll16 per split.
    auto stageA_hi = [&](int kt, int slot) {
        const char* p = (const char*)Ahi + kt * 16384 + tid * 16;
        char* d = (char*)&sAhi[slot][0] + tid * 16;
        gll16(p,        d);
        gll16(p + 8192, d + 8192);
    };
    auto stageA_lo = [&](int kt, int slot) {
        const char* p = (const char*)Alo + kt * 16384 + tid * 16;
        char* d = (char*)&sAlo[slot][0] + tid * 16;
        gll16(p,        d);
        gll16(p + 8192, d + 8192);
    };
    auto writeB = [&](int buf, float4 u, float4 v) {
        float f[8] = {u.x, u.y, u.z, u.w, v.x, v.y, v.z, v.w};
        U16x8 h, l;
#pragma unroll
        for (int i = 0; i < 8; ++i) {
            float a = f[i];
            xs_acc = fmaf(a, a, xs_acc);
            bf16_t hb = (bf16_t)a;
            h.bf[i] = hb;
            l.bf[i] = (bf16_t)(a - (float)hb);
        }
        *(uint4*)&sBhi[buf][bOffW] = h.u4;
        *(uint4*)&sBlo[buf][bOffW] = l.u4;
    };

    // fragment LDS offsets (ushort units), swizzle folded in
    int aOff[4], bOff[4];
#pragma unroll
    for (int f = 0; f < 4; ++f) {
        int row  = wr * 64 + f * 16 + l15;
        aOff[f]  = row * BK + ((l4 ^ ((row >> 1) & 3)) << 3);
        int col  = wc * 64 + f * 16 + l15;
        bOff[f]  = col * BK + ((l4 ^ ((col >> 1) & 3)) << 3);
    }

    // prologue: stage A(0)->slot0, A(1)->slot1; convert B(0); prefetch x(1)
    float4 p0, p1;
    stageA_hi(0, 0); stageA_lo(0, 0);
    stageA_hi(1, 1); stageA_lo(1, 1);
    p0 = *(const float4*)(xsrc);
    p1 = *(const float4*)(xsrc + 4);
    writeB(0, p0, p1);               // auto-vmcnt drains prologue queue; fine
    p0 = *(const float4*)(xsrc + BK);
    p1 = *(const float4*)(xsrc + BK + 4);
    __syncthreads();                 // full drain once (prologue only)

    f32x4 acc[4][4];
#pragma unroll
    for (int i = 0; i < 4; ++i)
#pragma unroll
        for (int q = 0; q < 4; ++q) acc[i][q] = (f32x4){0.f, 0.f, 0.f, 0.f};

    int sa = 0;                      // slot of kt (kt % 3)
    for (int kt = 0; kt < NT; ++kt) {
        const int  sb  = kt & 1;
        const int  s2  = (sa == 0) ? 2 : sa - 1;   // slot of kt+2
        const bool pf1 = (kt + 1 < NT);
        const bool pf2 = (kt + 2 < NT);

        U16x8 ah[4], al[4], bh[4], bl[4];

        // ---- ph0: reads {ah x4, b01}, gll A(kt+2) hi; MFMA hh+hl fj01 ----
#pragma unroll
        for (int f = 0; f < 4; ++f) ah[f].u4 = *(const uint4*)&sAhi[sa][aOff[f]];
        bh[0].u4 = *(const uint4*)&sBhi[sb][bOff[0]];
        bl[0].u4 = *(const uint4*)&sBlo[sb][bOff[0]];
        bh[1].u4 = *(const uint4*)&sBhi[sb][bOff[1]];
        bl[1].u4 = *(const uint4*)&sBlo[sb][bOff[1]];
        if (pf2) stageA_hi(kt + 2, s2);
        SCHB();
        BAR();
        LGKM0();
        __builtin_amdgcn_s_setprio(1);
#pragma unroll
        for (int fi = 0; fi < 4; ++fi) MFMA(acc[fi][0], ah[fi], bh[0]);
#pragma unroll
        for (int fi = 0; fi < 4; ++fi) MFMA(acc[fi][1], ah[fi], bh[1]);
#pragma unroll
        for (int fi = 0; fi < 4; ++fi) MFMA(acc[fi][0], ah[fi], bl[0]);
#pragma unroll
        for (int fi = 0; fi < 4; ++fi) MFMA(acc[fi][1], ah[fi], bl[1]);
        __builtin_amdgcn_s_setprio(0);
        BAR();

        // ---- ph1: reads {b23}, gll A(kt+2) lo; MFMA hh+hl fj23 ----
        bh[2].u4 = *(const uint4*)&sBhi[sb][bOff[2]];
        bl[2].u4 = *(const uint4*)&sBlo[sb][bOff[2]];
        bh[3].u4 = *(const uint4*)&sBhi[sb][bOff[3]];
        bl[3].u4 = *(const uint4*)&sBlo[sb][bOff[3]];
        if (pf2) stageA_lo(kt + 2, s2);
        SCHB();
        BAR();
        LGKM0();
        __builtin_amdgcn_s_setprio(1);
#pragma unroll
        for (int fi = 0; fi < 4; ++fi) MFMA(acc[fi][2], ah[fi], bh[2]);
#pragma unroll
        for (int fi = 0; fi < 4; ++fi) MFMA(acc[fi][3], ah[fi], bh[3]);
#pragma unroll
        for (int fi = 0; fi < 4; ++fi) MFMA(acc[fi][2], ah[fi], bl[2]);
#pragma unroll
        for (int fi = 0; fi < 4; ++fi) MFMA(acc[fi][3], ah[fi], bl[3]);
        __builtin_amdgcn_s_setprio(0);
        BAR();

        // ---- ph2: reads {al x4}; convert+write B(kt+1); bload(kt+2);
        //           MFMA lh fj0-3; VMCNT(6); BAR ----
#pragma unroll
        for (int f = 0; f < 4; ++f) al[f].u4 = *(const uint4*)&sAlo[sa][aOff[f]];
        if (pf1) writeB(sb ^ 1, p0, p1);   // auto-vmcnt proves b(kt+1) AND A(kt+1) glls
        SCHB();
        if (pf2) {                          // regs free after convert (strict order)
            const float* p = xsrc + (kt + 2) * BK;
            p0 = *(const float4*)p;
            p1 = *(const float4*)(p + 4);
        }
        SCHB();
        BAR();
        LGKM0();                            // own al reads + B ds_writes done
        __builtin_amdgcn_s_setprio(1);
#pragma unroll
        for (int fj = 0; fj < 4; ++fj)
#pragma unroll
            for (int fi = 0; fi < 4; ++fi) MFMA(acc[fi][fj], al[fi], bh[fj]);
        __builtin_amdgcn_s_setprio(0);
        if (pf2) { VMCNT(6); } else { VMCNT(0); }
        BAR();

        sa = (sa == 2) ? 0 : sa + 1;
    }

    // x_sq: 4 threads per column
    {
        float v = xs_acc;
        v += __shfl_xor(v, 1);
        v += __shfl_xor(v, 2);
        if (bq == 0) sXsq[bcol] = v;
    }
    __syncthreads();

    // epilogue: distances, argmin, loss
    const int colBase = wc * 64;
    float xs[4];
    f32x4 cs[4];
#pragma unroll
    for (int f = 0; f < 4; ++f) {
        xs[f] = sXsq[colBase + f * 16 + l15];
        cs[f] = *(const f32x4*)&sCsq[wr * 64 + f * 16 + l4 * 4];
    }

    float lsum = 0.f;
    float bestv[4];
    int   bestr[4];
#pragma unroll
    for (int f = 0; f < 4; ++f) { bestv[f] = 3.4e38f; bestr[f] = 0; }

#pragma unroll
    for (int fi = 0; fi < 4; ++fi) {
        const int rowB = wr * 64 + fi * 16 + l4 * 4;
#pragma unroll
        for (int fj = 0; fj < 4; ++fj) {
            const int col = blk * BN + colBase + fj * 16 + l15;
            float* outp = out_dist + (size_t)rowB * N_PTS + col;
#pragma unroll
            for (int j = 0; j < 4; ++j) {
                float d = cs[fi][j] + xs[fj] - 2.0f * acc[fi][fj][j];
                outp[(size_t)j * N_PTS] = d;
                lsum += d;
                int r = rowB + j;
                if (d < bestv[fj]) { bestv[fj] = d; bestr[fj] = r; }
            }
        }
    }

    // wave argmin over the wave's 64 rows (lanes l, l^16, l^32 share a column)
#pragma unroll
    for (int fj = 0; fj < 4; ++fj) {
#pragma unroll
        for (int m = 16; m <= 32; m <<= 1) {
            float ov = __shfl_xor(bestv[fj], m);
            int   orr = __shfl_xor(bestr[fj], m);
            if (ov < bestv[fj] || (ov == bestv[fj] && orr < bestr[fj])) {
                bestv[fj] = ov; bestr[fj] = orr;
            }
        }
        if (lane < 16) {
            sRedV[wr * BN + colBase + fj * 16 + lane] = bestv[fj];
            sRedI[wr * BN + colBase + fj * 16 + lane] = bestr[fj];
        }
    }

#pragma unroll
    for (int off = 1; off < 64; off <<= 1) lsum += __shfl_xor(lsum, off);
    if (lane == 0) sWsum[w] = lsum;
    __syncthreads();

    if (tid < BN) {
        float bv = sRedV[tid];
        int   br = sRedI[tid];
#pragma unroll
        for (int q = 1; q < 4; ++q) {
            float v = sRedV[q * BN + tid];
            int   r = sRedI[q * BN + tid];
            if (v < bv || (v == bv && r < br)) { bv = v; br = r; }
        }
        out_assign[blk * BN + tid] = (float)br;
    }
    if (tid == 0) {
        float t = 0.f;
#pragma unroll
        for (int q = 0; q < 8; ++q) t += sWsum[q];
        partials[blk] = t;
    }
}

// ---------------------------------------------------------------------------
// Kernel 2: deterministic loss reduction over 512 block partials.
// ---------------------------------------------------------------------------
__global__ __launch_bounds__(512) void km_fin(const float* __restrict__ partials,
                                              float* __restrict__ out_loss) {
    __shared__ float ws[8];
    const int t = threadIdx.x;
    float v = partials[t];
#pragma unroll
    for (int off = 1; off < 64; off <<= 1) v += __shfl_xor(v, off);
    if ((t & 63) == 0) ws[t >> 6] = v;
    __syncthreads();
    if (t == 0) {
        float s = 0.f;
#pragma unroll
        for (int i = 0; i < 8; ++i) s += ws[i];
        out_loss[0] = s / 16777216.0f;   // mean over K*N
    }
}

extern "C" void kernel_launch(void* const* d_in, const int* in_sizes, int n_in,
                              void* d_out, int out_size, void* d_ws, size_t ws_size,
                              hipStream_t stream) {
    const float* x    = (const float*)d_in[0];
    const float* cent = (const float*)d_in[1];

    float* out        = (float*)d_out;
    float* out_dist   = out;                                  // [256][65536]
    float* out_assign = out + (size_t)K_CL * N_PTS;           // [65536] as float
    float* out_loss   = out_assign + N_PTS;                   // [1]

    char*   ws       = (char*)d_ws;
    float*  csq      = (float*)ws;                            // 256 f32
    float*  partials = (float*)(ws + 1024);                   // 512 f32
    ushort* Ahi      = (ushort*)(ws + 4096);                  // 512 KB
    ushort* Alo      = (ushort*)(ws + 4096 + 524288);         // 512 KB

    km_prep<<<dim3(K_CL), dim3(128), 0, stream>>>(cent, Ahi, Alo, csq);
    km_main<<<dim3(N_PTS / BN), dim3(THREADS), 0, stream>>>(
        x, Ahi, Alo, csq, out_dist, out_assign, partials);
    km_fin<<<dim3(1), dim3(512), 0, stream>>>(partials, out_loss);
}